// Round 7
// baseline (658.349 us; speedup 1.0000x reference)
//
#include <hip/hip_runtime.h>
#include <math.h>

namespace {

constexpr int kB = 512, kI = 1152, kD = 8, kJ = 10, kC = 16;
constexpr int THREADS = 512;                // 8 waves
constexpr int ROWS = kI / (THREADS / 4);    // 9 i-rows per thread
constexpr float EPS = 1e-7f;

// One (batch, j) pair per block. Thread (g = t>>2, c4 = t&3) owns i-rows
// {g + 128*it, it<9} and channels {4*c4..4*c4+3}. x_hat lives in registers
// (36 floats/thread, statically indexed).
//
// Register-budget lesson (rounds 3-5): the allocator defaults to the 128-VGPR
// occupancy tier and SPILLS this kernel (WRITE_SIZE 1.1 GB vs 320 KB output;
// the scratch bounce IS the runtime). Live state is ~110 floats but the
// scheduler pipelines phase-1's 72 float4 W-loads, pushing demand past 128.
// __launch_bounds__(512, 1): 8-wave block on 4 SIMDs -> 2 waves/SIMD -> cap
// rises to 256 VGPRs. Spill-free > occupancy here.
__launch_bounds__(THREADS, 1)
__global__ void digitcaps_fused(const float* __restrict__ x,
                                const float* __restrict__ W,
                                float* __restrict__ out) {
  __shared__ float sredS[8][kC];       // per-wave partial s (512 B)
  __shared__ float sredZ[8];
  __shared__ float sredM[8];

  const int t    = threadIdx.x;
  const int lane = t & 63;
  const int wid  = t >> 6;
  const int c4   = t & 3;
  const int g    = t >> 2;

  const int bid = blockIdx.x;
  const int j   = bid >> 9;            // j-major: 512 consecutive blocks share W[j]
  const int b   = bid & 511;           // batch index

  float xh[ROWS][4];                   // register-resident x_hat fragments

  // ---------------- Phase 1: x_hat[b,j,i,c] = sum_d x[b,i,d]*W[j,i,d,c] -----
  #pragma unroll
  for (int it = 0; it < ROWS; ++it) {
    const int i = it * 128 + g;
    const float* Wp = W + (size_t)(j * kI + i) * (kD * kC) + (c4 << 2);
    const float4* xp = reinterpret_cast<const float4*>(
        x + (size_t)(b * kI + i) * kD);
    const float4 v0 = xp[0], v1 = xp[1];
    float xr[kD];
    xr[0] = v0.x; xr[1] = v0.y; xr[2] = v0.z; xr[3] = v0.w;
    xr[4] = v1.x; xr[5] = v1.y; xr[6] = v1.z; xr[7] = v1.w;
    float a0 = 0.f, a1 = 0.f, a2 = 0.f, a3 = 0.f;
    #pragma unroll
    for (int d = 0; d < kD; ++d) {
      const float4 w = *reinterpret_cast<const float4*>(Wp + d * kC);
      a0 += xr[d] * w.x;
      a1 += xr[d] * w.y;
      a2 += xr[d] * w.z;
      a3 += xr[d] * w.w;
    }
    xh[it][0] = a0; xh[it][1] = a1; xh[it][2] = a2; xh[it][3] = a3;
  }

  // ---------------- Phase 2: 3 routing iterations, register math ------------
  float bl[ROWS];
  #pragma unroll
  for (int r = 0; r < ROWS; ++r) bl[r] = 0.f;

  #pragma unroll
  for (int itr = 0; itr < 3; ++itr) {
    // --- softmax max over i: local 9 -> g-butterfly -> cross-wave (LDS) ---
    float mm = bl[0];
    #pragma unroll
    for (int r = 1; r < ROWS; ++r) mm = fmaxf(mm, bl[r]);
    #pragma unroll
    for (int off = 4; off < 64; off <<= 1)
      mm = fmaxf(mm, __shfl_xor(mm, off, 64));
    if (lane == 0) sredM[wid] = mm;
    __syncthreads();                                   // barrier A
    float m = sredM[0];
    #pragma unroll
    for (int w = 1; w < 8; ++w) m = fmaxf(m, sredM[w]);

    // --- e_i, partial Z, partial s over own 4 channels ---
    float zp = 0.f, sp0 = 0.f, sp1 = 0.f, sp2 = 0.f, sp3 = 0.f;
    #pragma unroll
    for (int r = 0; r < ROWS; ++r) {
      const float e = expf(bl[r] - m);
      zp  += e;
      sp0 += e * xh[r][0];
      sp1 += e * xh[r][1];
      sp2 += e * xh[r][2];
      sp3 += e * xh[r][3];
    }
    #pragma unroll
    for (int off = 4; off < 64; off <<= 1) {           // reduce over g in-wave
      zp  += __shfl_xor(zp,  off, 64);
      sp0 += __shfl_xor(sp0, off, 64);
      sp1 += __shfl_xor(sp1, off, 64);
      sp2 += __shfl_xor(sp2, off, 64);
      sp3 += __shfl_xor(sp3, off, 64);
    }
    if (lane < 4) {                                    // lane l holds c4=l partial
      float4 v4; v4.x = sp0; v4.y = sp1; v4.z = sp2; v4.w = sp3;
      *reinterpret_cast<float4*>(&sredS[wid][lane * 4]) = v4;
    }
    if (lane == 0) sredZ[wid] = zp;
    __syncthreads();                                   // barrier B

    // --- combine wave partials; squash (uniform across block) ---
    float Z = 0.f;
    #pragma unroll
    for (int w = 0; w < 8; ++w) Z += sredZ[w];
    float s0 = 0.f, s1 = 0.f, s2 = 0.f, s3 = 0.f;
    #pragma unroll
    for (int w = 0; w < 8; ++w) {
      const float4 v4 = *reinterpret_cast<const float4*>(&sredS[w][c4 * 4]);
      s0 += v4.x; s1 += v4.y; s2 += v4.z; s3 += v4.w;
    }
    const float invZ = 1.f / Z;
    s0 *= invZ; s1 *= invZ; s2 *= invZ; s3 *= invZ;
    float pq = s0 * s0 + s1 * s1 + s2 * s2 + s3 * s3;
    pq += __shfl_xor(pq, 1, 64);                       // sum ssq across c4
    pq += __shfl_xor(pq, 2, 64);
    const float nrm = sqrtf(pq);
    const float fac = pq / ((1.f + pq) * (nrm + EPS));

    if (itr < 2) {
      // --- agreement: b_i += dot(v, x_hat[i,:]) ---
      const float vc0 = fac * s0, vc1 = fac * s1, vc2 = fac * s2, vc3 = fac * s3;
      #pragma unroll
      for (int r = 0; r < ROWS; ++r) {
        float dp = vc0 * xh[r][0] + vc1 * xh[r][1]
                 + vc2 * xh[r][2] + vc3 * xh[r][3];
        dp += __shfl_xor(dp, 1, 64);                   // sum across c4 (same g)
        dp += __shfl_xor(dp, 2, 64);
        bl[r] += dp;
      }
    } else {
      // --- final write: thread t<4 writes its 4 channels as float4 ---
      if (t < 4) {
        float4 o;
        o.x = fac * s0; o.y = fac * s1; o.z = fac * s2; o.w = fac * s3;
        *reinterpret_cast<float4*>(out + ((size_t)b * kJ + j) * kC + t * 4) = o;
      }
    }
    // Barrier safety: sredM is written pre-A / read pre-B; next write is after
    // the next iteration's A. sredZ/sredS written pre-B / read pre-next-A.
  }
}

}  // namespace

extern "C" void kernel_launch(void* const* d_in, const int* in_sizes, int n_in,
                              void* d_out, int out_size, void* d_ws, size_t ws_size,
                              hipStream_t stream) {
  (void)in_sizes; (void)n_in; (void)d_ws; (void)ws_size; (void)out_size;
  const float* x = reinterpret_cast<const float*>(d_in[0]);
  const float* W = reinterpret_cast<const float*>(d_in[1]);
  float* out = reinterpret_cast<float*>(d_out);
  const int grid = kB * kJ;  // 5120 blocks, j-major
  digitcaps_fused<<<grid, THREADS, 0, stream>>>(x, W, out);
}

// Round 8
// 245.504 us; speedup vs baseline: 2.6816x; 2.6816x over previous
//
#include <hip/hip_runtime.h>
#include <math.h>

namespace {

constexpr int kB = 512, kI = 1152, kD = 8, kJ = 10, kC = 16;
constexpr int THREADS = 512;                // 8 waves
constexpr int TB = 2;                       // batches per block
constexpr int ROWS = kI / (THREADS / 4);    // 9 i-rows per thread
constexpr float EPS = 1e-7f;

// Lesson (rounds 3-7): the allocator pins this kernel at the 128-VGPR tier no
// matter what __launch_bounds__ says, and spills any design whose per-thread
// state + pipelined loads exceed it (the 1-2 GB scratch bounce WAS the
// runtime). So x_hat lives in LDS, not registers. Unlike round 1, phase 1
// computes directly in the phase-2 ownership layout (thread (g=t>>2, c4=t&3)
// owns rows {g+128*it} channels {4c4..4c4+3}) -> no transpose pass, and all
// LDS traffic is ds_read/write_b128 with a wave covering 1 KB contiguous ->
// conflict-free with NO padding. TB=2 halves W L2-traffic (both batches share
// every W load and every barrier); 145 KB LDS -> 1 block/CU.
__launch_bounds__(THREADS)
__global__ void digitcaps_fused(const float* __restrict__ x,
                                const float* __restrict__ W,
                                float* __restrict__ out) {
  __shared__ float xhat[TB][kI][kC];   // 144 KB, [i][c] row stride 64 B
  __shared__ float sredS[TB][8][kC];   // per-wave partial s (1 KB)
  __shared__ float sredZ[TB][8];
  __shared__ float sredM[TB][8];

  const int t    = threadIdx.x;
  const int lane = t & 63;
  const int wid  = t >> 6;
  const int c4   = t & 3;
  const int g    = t >> 2;

  const int bid = blockIdx.x;
  const int j   = bid >> 8;            // j-major: 256 consecutive blocks share W[j]
  const int b0  = (bid & 255) * TB;

  // ---------------- Phase 1: x_hat[b,j,i,c] = sum_d x[b,i,d]*W[j,i,d,c] -----
  // Partial unroll: reg arrays inside are never indexed by 'it', so unroll 3
  // is safe and caps the scheduler's load-pipelining register demand.
  #pragma unroll 3
  for (int it = 0; it < ROWS; ++it) {
    const int i = it * 128 + g;
    const float* Wp = W + (size_t)(j * kI + i) * (kD * kC) + (c4 << 2);
    float xr[TB][kD];
    #pragma unroll
    for (int tb = 0; tb < TB; ++tb) {
      const float4* xp = reinterpret_cast<const float4*>(
          x + (size_t)((b0 + tb) * kI + i) * kD);
      const float4 v0 = xp[0], v1 = xp[1];
      xr[tb][0] = v0.x; xr[tb][1] = v0.y; xr[tb][2] = v0.z; xr[tb][3] = v0.w;
      xr[tb][4] = v1.x; xr[tb][5] = v1.y; xr[tb][6] = v1.z; xr[tb][7] = v1.w;
    }
    float a[TB][4] = {};
    #pragma unroll
    for (int d = 0; d < kD; ++d) {
      const float4 w = *reinterpret_cast<const float4*>(Wp + d * kC);  // shared by both batches
      #pragma unroll
      for (int tb = 0; tb < TB; ++tb) {
        a[tb][0] += xr[tb][d] * w.x;
        a[tb][1] += xr[tb][d] * w.y;
        a[tb][2] += xr[tb][d] * w.z;
        a[tb][3] += xr[tb][d] * w.w;
      }
    }
    #pragma unroll
    for (int tb = 0; tb < TB; ++tb) {
      float4 v4;
      v4.x = a[tb][0]; v4.y = a[tb][1]; v4.z = a[tb][2]; v4.w = a[tb][3];
      *reinterpret_cast<float4*>(&xhat[tb][i][c4 * 4]) = v4;  // b128, conflict-free
    }
  }
  __syncthreads();                                     // phase-1 -> phase-2

  // ---------------- Phase 2: 3 routing iterations -------------------------
  float bl[TB][ROWS];                  // logits, registers (18 floats, static)
  #pragma unroll
  for (int tb = 0; tb < TB; ++tb)
    #pragma unroll
    for (int r = 0; r < ROWS; ++r) bl[tb][r] = 0.f;

  #pragma unroll
  for (int itr = 0; itr < 3; ++itr) {
    // --- softmax max over i: local 9 -> g-butterfly -> cross-wave ---
    #pragma unroll
    for (int tb = 0; tb < TB; ++tb) {
      float mm = bl[tb][0];
      #pragma unroll
      for (int r = 1; r < ROWS; ++r) mm = fmaxf(mm, bl[tb][r]);
      #pragma unroll
      for (int off = 4; off < 64; off <<= 1)
        mm = fmaxf(mm, __shfl_xor(mm, off, 64));
      if (lane == 0) sredM[tb][wid] = mm;
    }
    __syncthreads();                                   // barrier A
    float m[TB];
    #pragma unroll
    for (int tb = 0; tb < TB; ++tb) {
      float mm = sredM[tb][0];
      #pragma unroll
      for (int w = 1; w < 8; ++w) mm = fmaxf(mm, sredM[tb][w]);
      m[tb] = mm;
    }

    // --- e_i, partial Z, partial s over own 4 channels (xhat from LDS) ---
    float zp[TB], sp[TB][4];
    #pragma unroll
    for (int tb = 0; tb < TB; ++tb) {
      zp[tb] = 0.f; sp[tb][0] = sp[tb][1] = sp[tb][2] = sp[tb][3] = 0.f;
      #pragma unroll
      for (int r = 0; r < ROWS; ++r) {
        const int i = r * 128 + g;
        const float4 h = *reinterpret_cast<const float4*>(&xhat[tb][i][c4 * 4]);
        const float e = expf(bl[tb][r] - m[tb]);
        zp[tb]    += e;
        sp[tb][0] += e * h.x; sp[tb][1] += e * h.y;
        sp[tb][2] += e * h.z; sp[tb][3] += e * h.w;
      }
    }
    #pragma unroll
    for (int off = 4; off < 64; off <<= 1) {           // reduce over g in-wave
      #pragma unroll
      for (int tb = 0; tb < TB; ++tb) {
        zp[tb]    += __shfl_xor(zp[tb],    off, 64);
        sp[tb][0] += __shfl_xor(sp[tb][0], off, 64);
        sp[tb][1] += __shfl_xor(sp[tb][1], off, 64);
        sp[tb][2] += __shfl_xor(sp[tb][2], off, 64);
        sp[tb][3] += __shfl_xor(sp[tb][3], off, 64);
      }
    }
    if (lane < 4) {                                    // lane l holds c4=l partial
      #pragma unroll
      for (int tb = 0; tb < TB; ++tb) {
        float4 v4;
        v4.x = sp[tb][0]; v4.y = sp[tb][1]; v4.z = sp[tb][2]; v4.w = sp[tb][3];
        *reinterpret_cast<float4*>(&sredS[tb][wid][lane * 4]) = v4;
      }
    }
    if (lane == 0) {
      #pragma unroll
      for (int tb = 0; tb < TB; ++tb) sredZ[tb][wid] = zp[tb];
    }
    __syncthreads();                                   // barrier B

    // --- combine wave partials; squash; update or write ---
    #pragma unroll
    for (int tb = 0; tb < TB; ++tb) {
      float Z = 0.f;
      #pragma unroll
      for (int w = 0; w < 8; ++w) Z += sredZ[tb][w];
      float s0 = 0.f, s1 = 0.f, s2 = 0.f, s3 = 0.f;
      #pragma unroll
      for (int w = 0; w < 8; ++w) {                    // broadcast reads
        const float4 v4 = *reinterpret_cast<const float4*>(&sredS[tb][w][c4 * 4]);
        s0 += v4.x; s1 += v4.y; s2 += v4.z; s3 += v4.w;
      }
      const float invZ = 1.f / Z;
      s0 *= invZ; s1 *= invZ; s2 *= invZ; s3 *= invZ;
      float pq = s0 * s0 + s1 * s1 + s2 * s2 + s3 * s3;
      pq += __shfl_xor(pq, 1, 64);                     // sum ssq across c4
      pq += __shfl_xor(pq, 2, 64);
      const float nrm = sqrtf(pq);
      const float fac = pq / ((1.f + pq) * (nrm + EPS));

      if (itr < 2) {
        const float vc0 = fac * s0, vc1 = fac * s1, vc2 = fac * s2, vc3 = fac * s3;
        #pragma unroll
        for (int r = 0; r < ROWS; ++r) {
          const int i = r * 128 + g;
          const float4 h = *reinterpret_cast<const float4*>(&xhat[tb][i][c4 * 4]);
          float dp = vc0 * h.x + vc1 * h.y + vc2 * h.z + vc3 * h.w;
          dp += __shfl_xor(dp, 1, 64);                 // sum across c4 (same g)
          dp += __shfl_xor(dp, 2, 64);
          bl[tb][r] += dp;
        }
      } else {
        if (t < 4) {                                   // c4 = t, g = 0
          float4 o;
          o.x = fac * s0; o.y = fac * s1; o.z = fac * s2; o.w = fac * s3;
          *reinterpret_cast<float4*>(out + ((size_t)(b0 + tb) * kJ + j) * kC + t * 4) = o;
        }
      }
    }
    // Barrier safety: sredM written pre-A, read pre-B; next write after next A
    // (separated by B). sredS/Z written pre-B, read pre-next-A. xhat is
    // read-only after the phase-1 barrier.
  }
}

}  // namespace

extern "C" void kernel_launch(void* const* d_in, const int* in_sizes, int n_in,
                              void* d_out, int out_size, void* d_ws, size_t ws_size,
                              hipStream_t stream) {
  (void)in_sizes; (void)n_in; (void)d_ws; (void)ws_size; (void)out_size;
  const float* x = reinterpret_cast<const float*>(d_in[0]);
  const float* W = reinterpret_cast<const float*>(d_in[1]);
  float* out = reinterpret_cast<float*>(d_out);
  const int grid = (kB / TB) * kJ;  // 2560 blocks, j-major
  digitcaps_fused<<<grid, THREADS, 0, stream>>>(x, W, out);
}